// Round 14
// baseline (279.374 us; speedup 1.0000x reference)
//
#include <hip/hip_runtime.h>
#include <hip/hip_bf16.h>

typedef short short8 __attribute__((ext_vector_type(8)));
typedef float f32x4  __attribute__((ext_vector_type(4)));
typedef float f32x16 __attribute__((ext_vector_type(16)));

#define EMB   512
#define MEM   128
#define G3    384
#define CLS_K 640
#define KJ    640           // joint K = EMB + MEM
#define NKS   20            // K-steps of 32
#define ROWS  64
#define NTHR  512           // 8 waves: 2 row-groups x 4 col-groups
#define WB_CLS (G3 * KJ)    // cls rows offset in wb (shorts)

// LDS layout (bytes) -- 59.5 KB total => 2 blocks/CU
#define OFF_A    0          // 2 bufs x 4096: bf16 A, slot = q*64 + (row^q), 16B chunks
#define OFF_B    8192       // 2 bufs x 24576: bf16 B [chunk=kq*384+col][16B]
#define OFF_CLS  57344      // bf16 [2][512] cls emb rows
#define OFF_CLSM 59392      // f32 [2][128] cls mem rows
#define OFF_ELP  60416      // f32 [64][2] emb-logit partials
#define SMEM_SZ  60928
// nv tile f32 [64][132] (33792 B) reuses OFF_A/OFF_B region after the main loop

__device__ __forceinline__ short f2b(float f) {
  __hip_bfloat16 h = __float2bfloat16(f);
  return __builtin_bit_cast(short, h);
}
__device__ __forceinline__ float b2f(short s) {
  return __uint_as_float(((unsigned)(unsigned short)s) << 16);
}
__device__ __forceinline__ short8 cvt8(f32x4 a, f32x4 b) {
  short8 v;
  v[0] = f2b(a[0]); v[1] = f2b(a[1]); v[2] = f2b(a[2]); v[3] = f2b(a[3]);
  v[4] = f2b(b[0]); v[5] = f2b(b[1]); v[6] = f2b(b[2]); v[7] = f2b(b[3]);
  return v;
}
__device__ __forceinline__ float sigm(float x)     { return 1.f / (1.f + __expf(-x)); }
__device__ __forceinline__ float tanhfast(float x) { return 2.f / (1.f + __expf(-2.f * x)) - 1.f; }

__device__ __forceinline__ void gll16(const void* gsrc, void* ldst) {
  __builtin_amdgcn_global_load_lds(
      (const __attribute__((address_space(1))) unsigned int*)gsrc,
      (__attribute__((address_space(3))) unsigned int*)ldst, 16, 0, 0);
}

// ---- prep: wb in PER-STEP TILE ORDER: shorts at (kc*1536 + kq*384 + col)*8 + e
//      hold B[col][kc*32 + kq*8 + e]; + 2x512 cls emb rows at WB_CLS ----
__global__ void prep_w_kernel(const float* __restrict__ wih, const float* __restrict__ whh,
                              const float* __restrict__ wcls, short* __restrict__ outw) {
  int i = blockIdx.x * blockDim.x + threadIdx.x;
  const int nJ = G3 * KJ;
  const int nTot = nJ + 2 * EMB;
  if (i < nJ) {
    const int e  = i & 7;
    const int cc = (i >> 3) % 1536;
    const int kc = (i >> 3) / 1536;
    const int col = cc % G3;
    const int kq  = cc / G3;
    const int k = kc * 32 + kq * 8 + e;
    const float v = (k < EMB) ? wih[(size_t)col * EMB + k] : whh[(size_t)col * MEM + (k - EMB)];
    outw[i] = f2b(v);
  } else if (i < nTot) {
    const int j = i - nJ;
    const int r = j >> 9, k = j & 511;
    outw[i] = f2b(wcls[(size_t)r * CLS_K + k]);
  }
}

__global__ void bitmap_set_kernel(const int* __restrict__ ids, unsigned char* __restrict__ bm, int n) {
  int i = blockIdx.x * blockDim.x + threadIdx.x;
  if (i < n) bm[ids[i]] = 1;
}

__global__ void copy_bank_kernel(const f32x4* __restrict__ src, f32x4* __restrict__ dst,
                                 const unsigned char* __restrict__ bm, int n4) {
  int i = blockIdx.x * blockDim.x + threadIdx.x;
  int stride = gridDim.x * blockDim.x;
  for (; i < n4; i += stride) {
    if (bm && bm[i >> 5]) continue;
    dst[i] = src[i];
  }
}

template <bool ASYNC>
__global__ __launch_bounds__(NTHR, 4)
void fused_gru_kernel(const float* __restrict__ emb, const int* __restrict__ ids,
                      const float* __restrict__ bank,
                      const float* __restrict__ Wihf, const float* __restrict__ Whhf,
                      const float* __restrict__ bih,  const float* __restrict__ bhh,
                      const float* __restrict__ Wcls, const float* __restrict__ bcls,
                      const short* __restrict__ Wb,
                      float* __restrict__ out_logits, float* __restrict__ out_bank, int N) {
  __shared__ __align__(16) char smem[SMEM_SZ];

  const int t   = threadIdx.x;
  const int l   = t & 63;
  const int w   = t >> 6;       // 0..7
  const int wr  = w >> 2;       // row group (32 rows)
  const int wc  = w & 3;        // col group (32 m-cols)
  const int lk2 = l >> 5;
  const int l31 = l & 31;
  const int r0  = blockIdx.x * ROWS;

  // ---- epilogue per-lane row (lane l <-> block row l) ----
  int growE = r0 + l; if (growE > N - 1) growE = N - 1;
  const int gidE0 = ids[growE];

  // ---- A reg-staging map: threads 0..255, row=t>>2, chunk c=t&3 (32B per thread) ----
  const bool stager = t < 256;
  const int sRow = t >> 2;
  const int sC   = t & 3;
  int growA = r0 + sRow; if (growA > N - 1) growA = N - 1;
  const int gidA = ids[growA];
  const float* pEmbA  = emb  + (size_t)growA * EMB + sC * 8;
  const float* pBankA = bank + (size_t)gidA  * MEM + sC * 8;
  const int sSlot = sC * 64 + (sRow ^ sC);     // bank-spread slot

  f32x4 pa0, pa1;   // A prefetch regs (stager threads)

  // ---- stage cls tables ----
  if (t < 128) {
    short8 v;
    if constexpr (ASYNC) v = *(const short8*)(Wb + WB_CLS + t * 8);
    else {
      const int r = t >> 6, k = (t & 63) * 8;
      const float* p = Wcls + (size_t)r * CLS_K + k;
      v = cvt8(*(const f32x4*)p, *(const f32x4*)(p + 4));
    }
    *(short8*)(smem + OFF_CLS + t * 16) = v;
  } else if (t < 384) {
    const int i = t - 128;
    const int r = i >> 7, m = i & 127;
    ((float*)(smem + OFF_CLSM))[r * 128 + m] = Wcls[(size_t)r * CLS_K + EMB + m];
  }

  const int mcol = wc * 32 + l31;
  const float birv = bih[mcol] + bhh[mcol];
  const float bizv = bih[MEM + mcol] + bhh[MEM + mcol];
  const float binv = bih[2 * MEM + mcol];
  const float bhnv = bhh[2 * MEM + mcol];

  auto A_LOAD = [&](int kc) {
    if (stager) {
      const float* p = (kc < 16) ? (pEmbA + kc * 32) : (pBankA + (kc - 16) * 32);
      pa0 = *(const f32x4*)p;
      pa1 = *(const f32x4*)(p + 4);
    }
  };
  auto A_WRITE = [&](int kc) {
    if (stager)
      *(short8*)(smem + OFF_A + (kc & 1) * 4096 + sSlot * 16) = cvt8(pa0, pa1);
  };
  auto STAGE_B = [&](int kc) {
    const int buf = kc & 1;
    if constexpr (ASYNC) {
      const short* wbk = Wb + (size_t)kc * 12288;
#pragma unroll
      for (int s = 0; s < 3; ++s)
        gll16(wbk + (s * 512 + w * 64 + l) * 8,
              smem + OFF_B + buf * 24576 + (s * 512 + w * 64) * 16);
    } else {
#pragma unroll
      for (int s = 0; s < 3; ++s) {
        const int g = s * 512 + w * 64 + l;       // chunk = kq*384 + col
        const int col = g % G3, kq = g / G3;
        const int k = kc * 32 + kq * 8;
        const float* p = (k < EMB) ? (Wihf + (size_t)col * EMB + k)
                                   : (Whhf + (size_t)col * MEM + (k - EMB));
        short8 v = cvt8(*(const f32x4*)p, *(const f32x4*)(p + 4));
        *(short8*)(smem + OFF_B + buf * 24576 + g * 16) = v;
      }
    }
  };

  A_LOAD(0);
  STAGE_B(0);
  A_WRITE(0);
  __syncthreads();   // buf0 (A+B) ready

  f32x16 accR = {}, accZ = {}, accIN = {}, accHN = {};
  float clsL0 = 0.f, clsL1 = 0.f;

  const int arow  = wr * 32 + l31;
  const int bOffC = lk2 * 6144 + (wc * 32 + l31) * 16;   // + buf*24576 + ks*12288

  for (int kc = 0; kc < NKS; ++kc) {
    const int buf = kc & 1;
    if (kc + 1 < NKS) { A_LOAD(kc + 1); STAGE_B(kc + 1); }

    const char* ap = smem + OFF_A + buf * 4096;
    const char* bp = smem + OFF_B + buf * 24576;
#pragma unroll
    for (int ks = 0; ks < 2; ++ks) {
      const int q = ks * 2 + lk2;
      const short8 af = *(const short8*)(ap + (q * 64 + (arow ^ q)) * 16);
      if (wc == 0 && kc < 16) {         // emb-logit VALU dot on col-group 0
        const short8 w0 = *(const short8*)(smem + OFF_CLS + kc * 64 + ks * 32 + lk2 * 16);
        const short8 w1 = *(const short8*)(smem + OFF_CLS + 1024 + kc * 64 + ks * 32 + lk2 * 16);
#pragma unroll
        for (int i = 0; i < 8; ++i) {
          const float va = b2f(af[i]);
          clsL0 += va * b2f(w0[i]);
          clsL1 += va * b2f(w1[i]);
        }
      }
      const short8 b0 = *(const short8*)(bp + bOffC + ks * 12288);
      const short8 b1 = *(const short8*)(bp + bOffC + ks * 12288 + 2048);
      const short8 b2 = *(const short8*)(bp + bOffC + ks * 12288 + 4096);
      accR = __builtin_amdgcn_mfma_f32_32x32x16_bf16(af, b0, accR, 0, 0, 0);
      accZ = __builtin_amdgcn_mfma_f32_32x32x16_bf16(af, b1, accZ, 0, 0, 0);
      if (kc < 16) accIN = __builtin_amdgcn_mfma_f32_32x32x16_bf16(af, b2, accIN, 0, 0, 0);
      else         accHN = __builtin_amdgcn_mfma_f32_32x32x16_bf16(af, b2, accHN, 0, 0, 0);
    }
    if (kc + 1 < NKS) A_WRITE(kc + 1);   // cvt+write after compute: loads covered
    __syncthreads();   // buf^1 staged; buf consumed
  }

  // ---------------- GRU epilogue: math -> nv tile in LDS ----------------
  float* nvT = (float*)smem;          // [64][132] f32 (reuses A+B region)
  float hp[16];
#pragma unroll
  for (int j = 0; j < 16; ++j) {
    const int row32 = (j & 3) + 8 * (j >> 2) + 4 * lk2;    // 32x32 C/D row map
    const int gid = __shfl(gidE0, wr * 32 + row32);
    hp[j] = bank[(size_t)gid * MEM + mcol];
  }
#pragma unroll
  for (int j = 0; j < 16; ++j) {
    const int row32 = (j & 3) + 8 * (j >> 2) + 4 * lk2;
    const int row = wr * 32 + row32;
    const float rg = sigm(accR[j] + birv);
    const float zg = sigm(accZ[j] + bizv);
    const float ng = tanhfast(accIN[j] + binv + rg * (accHN[j] + bhnv));
    nvT[row * 132 + mcol] = (1.f - zg) * ng + zg * hp[j];
  }
  if (wc == 0) {
    const float e0 = clsL0 + __shfl_xor(clsL0, 32);
    const float e1 = clsL1 + __shfl_xor(clsL1, 32);
    if (l < 32) {
      float* elp = (float*)(smem + OFF_ELP);
      elp[(wr * 32 + l) * 2 + 0] = e0;
      elp[(wr * 32 + l) * 2 + 1] = e1;
    }
  }
  __syncthreads();

  // ---------------- coalesced scatter + logits ----------------
  {
    const int row = t >> 3, q = t & 7;
    const int gid = __shfl(gidE0, row);
    const f32x4 v0 = *(const f32x4*)(nvT + row * 132 + q * 16);
    const f32x4 v1 = *(const f32x4*)(nvT + row * 132 + q * 16 + 4);
    const f32x4 v2 = *(const f32x4*)(nvT + row * 132 + q * 16 + 8);
    const f32x4 v3 = *(const f32x4*)(nvT + row * 132 + q * 16 + 12);
    float* dst = out_bank + (size_t)gid * MEM + q * 16;
    *(f32x4*)dst = v0; *(f32x4*)(dst + 4) = v1; *(f32x4*)(dst + 8) = v2; *(f32x4*)(dst + 12) = v3;

    const float* cm0 = (const float*)(smem + OFF_CLSM) + q * 16;
    const float* cm1 = (const float*)(smem + OFF_CLSM) + 128 + q * 16;
    float lp0 = 0.f, lp1 = 0.f;
#pragma unroll
    for (int i = 0; i < 4; ++i) {
      lp0 += v0[i] * cm0[i] + v1[i] * cm0[4 + i] + v2[i] * cm0[8 + i] + v3[i] * cm0[12 + i];
      lp1 += v0[i] * cm1[i] + v1[i] * cm1[4 + i] + v2[i] * cm1[8 + i] + v3[i] * cm1[12 + i];
    }
#pragma unroll
    for (int s = 1; s < 8; s <<= 1) { lp0 += __shfl_xor(lp0, s); lp1 += __shfl_xor(lp1, s); }
    if (q == 0 && r0 + row < N) {
      const float* elp = (const float*)(smem + OFF_ELP);
      out_logits[(size_t)(r0 + row) * 2 + 0] = lp0 + elp[row * 2 + 0] + bcls[0];
      out_logits[(size_t)(r0 + row) * 2 + 1] = lp1 + elp[row * 2 + 1] + bcls[1];
    }
  }
}

extern "C" void kernel_launch(void* const* d_in, const int* in_sizes, int n_in,
                              void* d_out, int out_size, void* d_ws, size_t ws_size,
                              hipStream_t stream) {
  const float* emb  = (const float*)d_in[0];
  const int*   ids  = (const int*)d_in[1];
  const float* bank = (const float*)d_in[2];
  const float* wih  = (const float*)d_in[3];
  const float* whh  = (const float*)d_in[4];
  const float* bih  = (const float*)d_in[5];
  const float* bhh  = (const float*)d_in[6];
  const float* wcls = (const float*)d_in[7];
  const float* bcls = (const float*)d_in[8];

  const int N          = in_sizes[1];
  const int bank_elems = in_sizes[2];
  const int bank_rows  = bank_elems / MEM;
  const int n4         = bank_elems / 4;

  float* out_logits = (float*)d_out;
  float* out_bank   = (float*)d_out + (size_t)N * 2;

  const int wtot = G3 * KJ + 2 * EMB;
  const size_t wbytes  = (size_t)wtot * sizeof(short);
  const size_t bmbytes = ((size_t)bank_rows + 15) & ~15ull;

  const bool haveW  = ws_size >= wbytes;
  const bool haveBM = ws_size >= wbytes + bmbytes;

  short* wb = (short*)d_ws;
  unsigned char* bm = (unsigned char*)d_ws + wbytes;

  // 1) weight prep (tile-order layout for coalesced staging)
  if (haveW)
    prep_w_kernel<<<(wtot + 255) / 256, 256, 0, stream>>>(wih, whh, wcls, wb);

  // 2) fused joint-K GEMM (bf16 A+B in LDS, split reg-staged A, 2 blocks/CU)
  const int nb = (N + ROWS - 1) / ROWS;
  if (haveW)
    fused_gru_kernel<true><<<nb, NTHR, 0, stream>>>(emb, ids, bank, wih, whh, bih, bhh,
                                                    wcls, bcls, wb, out_logits, out_bank, N);
  else
    fused_gru_kernel<false><<<nb, NTHR, 0, stream>>>(emb, ids, bank, wih, whh, bih, bhh,
                                                     wcls, bcls, nullptr, out_logits, out_bank, N);

  // 3) copy non-active bank rows (disjoint from scatter rows)
  if (haveBM) {
    hipMemsetAsync(bm, 0, bmbytes, stream);
    bitmap_set_kernel<<<(N + 255) / 256, 256, 0, stream>>>(ids, bm, N);
    copy_bank_kernel<<<4096, 256, 0, stream>>>((const f32x4*)bank, (f32x4*)out_bank, bm, n4);
  } else {
    copy_bank_kernel<<<4096, 256, 0, stream>>>((const f32x4*)bank, (f32x4*)out_bank, nullptr, n4);
  }
}

// Round 15
// 261.391 us; speedup vs baseline: 1.0688x; 1.0688x over previous
//
#include <hip/hip_runtime.h>
#include <hip/hip_bf16.h>

typedef short short8 __attribute__((ext_vector_type(8)));
typedef float f32x4  __attribute__((ext_vector_type(4)));
typedef float f32x16 __attribute__((ext_vector_type(16)));

#define EMB   512
#define MEM   128
#define G3    384
#define CLS_K 640
#define KJ    640           // joint K = EMB + MEM
#define NKS   20            // K-steps of 32
#define ROWS  64
#define NTHR  512           // 8 waves: 2 row-groups x 4 col-groups
#define WB_CLS (G3 * KJ)    // cls rows offset in wb (shorts)

// LDS layout (bytes) -- 67.5 KB total => 2 blocks/CU
#define OFF_A    0          // 2 bufs x 8192: fp32 A [64 rows][8 chunks, XOR-swz]
#define OFF_B    16384      // 2 bufs x 24576: bf16 B [chunk=kq*384+col][16B]
#define OFF_CLS  65536      // bf16 [2][512] cls emb rows
#define OFF_CLSM 67584      // f32 [2][128] cls mem rows
#define OFF_ELP  68608      // f32 [64][2] emb-logit partials
#define SMEM_SZ  69120
// nv tile f32 [64][132] (33792 B) reuses OFF_A/OFF_B region after the main loop

__device__ __forceinline__ short f2b(float f) {
  __hip_bfloat16 h = __float2bfloat16(f);
  return __builtin_bit_cast(short, h);
}
__device__ __forceinline__ float b2f(short s) {
  return __uint_as_float(((unsigned)(unsigned short)s) << 16);
}
__device__ __forceinline__ short8 cvt8(f32x4 a, f32x4 b) {
  short8 v;
  v[0] = f2b(a[0]); v[1] = f2b(a[1]); v[2] = f2b(a[2]); v[3] = f2b(a[3]);
  v[4] = f2b(b[0]); v[5] = f2b(b[1]); v[6] = f2b(b[2]); v[7] = f2b(b[3]);
  return v;
}
__device__ __forceinline__ float sigm(float x)     { return 1.f / (1.f + __expf(-x)); }
__device__ __forceinline__ float tanhfast(float x) { return 2.f / (1.f + __expf(-2.f * x)) - 1.f; }

__device__ __forceinline__ void gll16(const void* gsrc, void* ldst) {
  __builtin_amdgcn_global_load_lds(
      (const __attribute__((address_space(1))) unsigned int*)gsrc,
      (__attribute__((address_space(3))) unsigned int*)ldst, 16, 0, 0);
}

// ---- prep: wb in PER-STEP TILE ORDER: shorts at (kc*1536 + kq*384 + col)*8 + e
//      hold B[col][kc*32 + kq*8 + e]; + 2x512 cls emb rows at WB_CLS ----
__global__ void prep_w_kernel(const float* __restrict__ wih, const float* __restrict__ whh,
                              const float* __restrict__ wcls, short* __restrict__ outw) {
  int i = blockIdx.x * blockDim.x + threadIdx.x;
  const int nJ = G3 * KJ;
  const int nTot = nJ + 2 * EMB;
  if (i < nJ) {
    const int e  = i & 7;
    const int cc = (i >> 3) % 1536;
    const int kc = (i >> 3) / 1536;
    const int col = cc % G3;
    const int kq  = cc / G3;
    const int k = kc * 32 + kq * 8 + e;
    const float v = (k < EMB) ? wih[(size_t)col * EMB + k] : whh[(size_t)col * MEM + (k - EMB)];
    outw[i] = f2b(v);
  } else if (i < nTot) {
    const int j = i - nJ;
    const int r = j >> 9, k = j & 511;
    outw[i] = f2b(wcls[(size_t)r * CLS_K + k]);
  }
}

__global__ void bitmap_set_kernel(const int* __restrict__ ids, unsigned char* __restrict__ bm, int n) {
  int i = blockIdx.x * blockDim.x + threadIdx.x;
  if (i < n) bm[ids[i]] = 1;
}

__global__ void copy_bank_kernel(const f32x4* __restrict__ src, f32x4* __restrict__ dst,
                                 const unsigned char* __restrict__ bm, int n4) {
  int i = blockIdx.x * blockDim.x + threadIdx.x;
  int stride = gridDim.x * blockDim.x;
  for (; i < n4; i += stride) {
    if (bm && bm[i >> 5]) continue;
    dst[i] = src[i];
  }
}

template <bool ASYNC>
__global__ __launch_bounds__(NTHR, 4)
void fused_gru_kernel(const float* __restrict__ emb, const int* __restrict__ ids,
                      const float* __restrict__ bank,
                      const float* __restrict__ Wihf, const float* __restrict__ Whhf,
                      const float* __restrict__ bih,  const float* __restrict__ bhh,
                      const float* __restrict__ Wcls, const float* __restrict__ bcls,
                      const short* __restrict__ Wb,
                      float* __restrict__ out_logits, float* __restrict__ out_bank, int N) {
  __shared__ __align__(16) char smem[SMEM_SZ];

  const int t   = threadIdx.x;
  const int l   = t & 63;
  const int w   = t >> 6;       // 0..7
  const int wr  = w >> 2;       // row group (32 rows)
  const int wc  = w & 3;        // col group (32 m-cols)
  const int lk2 = l >> 5;
  const int l31 = l & 31;
  const int r0  = blockIdx.x * ROWS;

  // ---- epilogue per-lane row (lane l <-> block row l) ----
  int growE = r0 + l; if (growE > N - 1) growE = N - 1;
  const int gidE0 = ids[growE];

  // ---- A staging: 8 lanes/row; lane covers row w*8+(l>>3), source chunk XOR-pre-swizzled ----
  const int rowS = w * 8 + (l >> 3);
  const int chS  = (l & 7) ^ ((l >> 3) & 7);     // source chunk for this lane (involution)
  int growS = r0 + rowS; if (growS > N - 1) growS = N - 1;
  const int gidS = ids[growS];
  const float* pEmbRow  = emb  + (size_t)growS * EMB + chS * 4;
  const float* pBankRow = bank + (size_t)gidS  * MEM + chS * 4;

  // ---- stage cls tables ----
  if (t < 128) {
    short8 v;
    if constexpr (ASYNC) v = *(const short8*)(Wb + WB_CLS + t * 8);
    else {
      const int r = t >> 6, k = (t & 63) * 8;
      const float* p = Wcls + (size_t)r * CLS_K + k;
      v = cvt8(*(const f32x4*)p, *(const f32x4*)(p + 4));
    }
    *(short8*)(smem + OFF_CLS + t * 16) = v;
  } else if (t < 384) {
    const int i = t - 128;
    const int r = i >> 7, m = i & 127;
    ((float*)(smem + OFF_CLSM))[r * 128 + m] = Wcls[(size_t)r * CLS_K + EMB + m];
  }

  const int mcol = wc * 32 + l31;
  const float birv = bih[mcol] + bhh[mcol];
  const float bizv = bih[MEM + mcol] + bhh[MEM + mcol];
  const float binv = bih[2 * MEM + mcol];
  const float bhnv = bhh[2 * MEM + mcol];

  auto STAGE = [&](int kc) {
    const int buf = kc & 1;
    // A: lane-coalesced within rows (8x128B runs), XOR-pre-swizzled source
    const float* srcA = (kc < 16) ? (pEmbRow + kc * 32) : (pBankRow + (kc - 16) * 32);
    gll16(srcA, smem + OFF_A + buf * 8192 + w * 1024);
    if constexpr (ASYNC) {
      // B: wb is in tile order -> each wave reads 1KB consecutive (per-lane +l*16B)
      const short* wbk = Wb + (size_t)kc * 12288;
#pragma unroll
      for (int s = 0; s < 3; ++s)
        gll16(wbk + (s * 512 + w * 64 + l) * 8,
              smem + OFF_B + buf * 24576 + (s * 512 + w * 64) * 16);
    } else {
#pragma unroll
      for (int s = 0; s < 3; ++s) {
        const int g = s * 512 + w * 64 + l;       // chunk = kq*384 + col
        const int col = g % G3, kq = g / G3;
        const int k = kc * 32 + kq * 8;
        const float* p = (k < EMB) ? (Wihf + (size_t)col * EMB + k)
                                   : (Whhf + (size_t)col * MEM + (k - EMB));
        short8 v = cvt8(*(const f32x4*)p, *(const f32x4*)(p + 4));
        *(short8*)(smem + OFF_B + buf * 24576 + g * 16) = v;
      }
    }
  };

  STAGE(0);
  __syncthreads();   // buf0 ready

  f32x16 accR = {}, accZ = {}, accIN = {}, accHN = {};
  float clsL0 = 0.f, clsL1 = 0.f;

  const int arow = wr * 32 + l31;
  const int aswz = arow & 7;
  const int bOffC = lk2 * 6144 + (wc * 32 + l31) * 16;   // + buf*24576 + ks*12288

  for (int kc = 0; kc < NKS; ++kc) {
    const int buf = kc & 1;
    if (kc + 1 < NKS) STAGE(kc + 1);    // fills buf^1 while we read buf

    const char* ap = smem + OFF_A + buf * 8192 + arow * 128;
    const char* bp = smem + OFF_B + buf * 24576;
    __builtin_amdgcn_s_setprio(1);      // favor this wave through the LDS->MFMA cluster
#pragma unroll
    for (int ks = 0; ks < 2; ++ks) {
      const int c0 = ks * 4 + lk2 * 2;
      const f32x4 av0 = *(const f32x4*)(ap + ((c0 ^ aswz) << 4));
      const f32x4 av1 = *(const f32x4*)(ap + (((c0 + 1) ^ aswz) << 4));
      const short8 af = cvt8(av0, av1);
      if (wc == 0 && kc < 16) {         // emb-logit VALU dot on col-group 0
        const short8 w0 = *(const short8*)(smem + OFF_CLS + kc * 64 + ks * 32 + lk2 * 16);
        const short8 w1 = *(const short8*)(smem + OFF_CLS + 1024 + kc * 64 + ks * 32 + lk2 * 16);
#pragma unroll
        for (int i = 0; i < 4; ++i) {
          clsL0 += av0[i] * b2f(w0[i]) + av1[i] * b2f(w0[i + 4]);
          clsL1 += av0[i] * b2f(w1[i]) + av1[i] * b2f(w1[i + 4]);
        }
      }
      const short8 b0 = *(const short8*)(bp + bOffC + ks * 12288);
      const short8 b1 = *(const short8*)(bp + bOffC + ks * 12288 + 2048);
      const short8 b2 = *(const short8*)(bp + bOffC + ks * 12288 + 4096);
      accR = __builtin_amdgcn_mfma_f32_32x32x16_bf16(af, b0, accR, 0, 0, 0);
      accZ = __builtin_amdgcn_mfma_f32_32x32x16_bf16(af, b1, accZ, 0, 0, 0);
      if (kc < 16) accIN = __builtin_amdgcn_mfma_f32_32x32x16_bf16(af, b2, accIN, 0, 0, 0);
      else         accHN = __builtin_amdgcn_mfma_f32_32x32x16_bf16(af, b2, accHN, 0, 0, 0);
    }
    __builtin_amdgcn_s_setprio(0);
    __syncthreads();   // buf^1 staged; buf consumed
  }

  // ---------------- GRU epilogue: math -> nv tile in LDS ----------------
  float* nvT = (float*)smem;          // [64][132] f32 (reuses A+B region)
  float hp[16];
#pragma unroll
  for (int j = 0; j < 16; ++j) {
    const int row32 = (j & 3) + 8 * (j >> 2) + 4 * lk2;    // 32x32 C/D row map
    const int gid = __shfl(gidE0, wr * 32 + row32);
    hp[j] = bank[(size_t)gid * MEM + mcol];
  }
#pragma unroll
  for (int j = 0; j < 16; ++j) {
    const int row32 = (j & 3) + 8 * (j >> 2) + 4 * lk2;
    const int row = wr * 32 + row32;
    const float rg = sigm(accR[j] + birv);
    const float zg = sigm(accZ[j] + bizv);
    const float ng = tanhfast(accIN[j] + binv + rg * (accHN[j] + bhnv));
    nvT[row * 132 + mcol] = (1.f - zg) * ng + zg * hp[j];
  }
  if (wc == 0) {
    const float e0 = clsL0 + __shfl_xor(clsL0, 32);
    const float e1 = clsL1 + __shfl_xor(clsL1, 32);
    if (l < 32) {
      float* elp = (float*)(smem + OFF_ELP);
      elp[(wr * 32 + l) * 2 + 0] = e0;
      elp[(wr * 32 + l) * 2 + 1] = e1;
    }
  }
  __syncthreads();

  // ---------------- coalesced scatter + logits ----------------
  {
    const int row = t >> 3, q = t & 7;
    const int gid = __shfl(gidE0, row);
    const f32x4 v0 = *(const f32x4*)(nvT + row * 132 + q * 16);
    const f32x4 v1 = *(const f32x4*)(nvT + row * 132 + q * 16 + 4);
    const f32x4 v2 = *(const f32x4*)(nvT + row * 132 + q * 16 + 8);
    const f32x4 v3 = *(const f32x4*)(nvT + row * 132 + q * 16 + 12);
    float* dst = out_bank + (size_t)gid * MEM + q * 16;
    *(f32x4*)dst = v0; *(f32x4*)(dst + 4) = v1; *(f32x4*)(dst + 8) = v2; *(f32x4*)(dst + 12) = v3;

    const float* cm0 = (const float*)(smem + OFF_CLSM) + q * 16;
    const float* cm1 = (const float*)(smem + OFF_CLSM) + 128 + q * 16;
    float lp0 = 0.f, lp1 = 0.f;
#pragma unroll
    for (int i = 0; i < 4; ++i) {
      lp0 += v0[i] * cm0[i] + v1[i] * cm0[4 + i] + v2[i] * cm0[8 + i] + v3[i] * cm0[12 + i];
      lp1 += v0[i] * cm1[i] + v1[i] * cm1[4 + i] + v2[i] * cm1[8 + i] + v3[i] * cm1[12 + i];
    }
#pragma unroll
    for (int s = 1; s < 8; s <<= 1) { lp0 += __shfl_xor(lp0, s); lp1 += __shfl_xor(lp1, s); }
    if (q == 0 && r0 + row < N) {
      const float* elp = (const float*)(smem + OFF_ELP);
      out_logits[(size_t)(r0 + row) * 2 + 0] = lp0 + elp[row * 2 + 0] + bcls[0];
      out_logits[(size_t)(r0 + row) * 2 + 1] = lp1 + elp[row * 2 + 1] + bcls[1];
    }
  }
}

extern "C" void kernel_launch(void* const* d_in, const int* in_sizes, int n_in,
                              void* d_out, int out_size, void* d_ws, size_t ws_size,
                              hipStream_t stream) {
  const float* emb  = (const float*)d_in[0];
  const int*   ids  = (const int*)d_in[1];
  const float* bank = (const float*)d_in[2];
  const float* wih  = (const float*)d_in[3];
  const float* whh  = (const float*)d_in[4];
  const float* bih  = (const float*)d_in[5];
  const float* bhh  = (const float*)d_in[6];
  const float* wcls = (const float*)d_in[7];
  const float* bcls = (const float*)d_in[8];

  const int N          = in_sizes[1];
  const int bank_elems = in_sizes[2];
  const int bank_rows  = bank_elems / MEM;
  const int n4         = bank_elems / 4;

  float* out_logits = (float*)d_out;
  float* out_bank   = (float*)d_out + (size_t)N * 2;

  const int wtot = G3 * KJ + 2 * EMB;
  const size_t wbytes  = (size_t)wtot * sizeof(short);
  const size_t bmbytes = ((size_t)bank_rows + 15) & ~15ull;

  const bool haveW  = ws_size >= wbytes;
  const bool haveBM = ws_size >= wbytes + bmbytes;

  short* wb = (short*)d_ws;
  unsigned char* bm = (unsigned char*)d_ws + wbytes;

  // 1) weight prep (tile-order layout for coalesced staging)
  if (haveW)
    prep_w_kernel<<<(wtot + 255) / 256, 256, 0, stream>>>(wih, whh, wcls, wb);

  // 2) fused joint-K GEMM (coalesced staging, 2-buf, 2 blocks/CU, setprio MFMA cluster)
  const int nb = (N + ROWS - 1) / ROWS;
  if (haveW)
    fused_gru_kernel<true><<<nb, NTHR, 0, stream>>>(emb, ids, bank, wih, whh, bih, bhh,
                                                    wcls, bcls, wb, out_logits, out_bank, N);
  else
    fused_gru_kernel<false><<<nb, NTHR, 0, stream>>>(emb, ids, bank, wih, whh, bih, bhh,
                                                     wcls, bcls, nullptr, out_logits, out_bank, N);

  // 3) copy non-active bank rows (disjoint from scatter rows)
  if (haveBM) {
    hipMemsetAsync(bm, 0, bmbytes, stream);
    bitmap_set_kernel<<<(N + 255) / 256, 256, 0, stream>>>(ids, bm, N);
    copy_bank_kernel<<<4096, 256, 0, stream>>>((const f32x4*)bank, (f32x4*)out_bank, bm, n4);
  } else {
    copy_bank_kernel<<<4096, 256, 0, stream>>>((const f32x4*)bank, (f32x4*)out_bank, nullptr, n4);
  }
}

// Round 16
// 256.802 us; speedup vs baseline: 1.0879x; 1.0179x over previous
//
#include <hip/hip_runtime.h>
#include <hip/hip_bf16.h>

typedef short short8 __attribute__((ext_vector_type(8)));
typedef float f32x4  __attribute__((ext_vector_type(4)));
typedef float f32x16 __attribute__((ext_vector_type(16)));

#define EMB   512
#define MEM   128
#define G3    384
#define CLS_K 640
#define KJ    640           // joint K = EMB + MEM
#define NKS   20            // K-steps of 32
#define ROWS  64
#define NTHR  512           // 8 waves: 2 row-groups x 4 col-groups
#define WB_CLS (G3 * KJ)    // cls rows offset in wb (shorts)

// LDS layout (bytes) -- 67.5 KB total => 2 blocks/CU
#define OFF_A    0          // 2 bufs x 8192: fp32 A [64 rows][8 chunks, XOR-swz]
#define OFF_B    16384      // 2 bufs x 24576: bf16 B [chunk=kq*384+col][16B]
#define OFF_CLS  65536      // bf16 [2][512] cls emb rows
#define OFF_CLSM 67584      // f32 [2][128] cls mem rows
#define OFF_ELP  68608      // f32 [64][2] emb-logit partials
#define SMEM_SZ  69120
// nv tile f32 [64][132] (33792 B) reuses OFF_A/OFF_B region after the main loop

__device__ __forceinline__ short f2b(float f) {
  __hip_bfloat16 h = __float2bfloat16(f);
  return __builtin_bit_cast(short, h);
}
__device__ __forceinline__ float b2f(short s) {
  return __uint_as_float(((unsigned)(unsigned short)s) << 16);
}
__device__ __forceinline__ short8 cvt8(f32x4 a, f32x4 b) {
  short8 v;
  v[0] = f2b(a[0]); v[1] = f2b(a[1]); v[2] = f2b(a[2]); v[3] = f2b(a[3]);
  v[4] = f2b(b[0]); v[5] = f2b(b[1]); v[6] = f2b(b[2]); v[7] = f2b(b[3]);
  return v;
}
__device__ __forceinline__ float sigm(float x)     { return 1.f / (1.f + __expf(-x)); }
__device__ __forceinline__ float tanhfast(float x) { return 2.f / (1.f + __expf(-2.f * x)) - 1.f; }

__device__ __forceinline__ void gll16(const void* gsrc, void* ldst) {
  __builtin_amdgcn_global_load_lds(
      (const __attribute__((address_space(1))) unsigned int*)gsrc,
      (__attribute__((address_space(3))) unsigned int*)ldst, 16, 0, 0);
}

// ---- prep: wb in PER-STEP TILE ORDER: shorts at (kc*1536 + kq*384 + col)*8 + e
//      hold B[col][kc*32 + kq*8 + e]; + 2x512 cls emb rows at WB_CLS ----
__global__ void prep_w_kernel(const float* __restrict__ wih, const float* __restrict__ whh,
                              const float* __restrict__ wcls, short* __restrict__ outw) {
  int i = blockIdx.x * blockDim.x + threadIdx.x;
  const int nJ = G3 * KJ;
  const int nTot = nJ + 2 * EMB;
  if (i < nJ) {
    const int e  = i & 7;
    const int cc = (i >> 3) % 1536;
    const int kc = (i >> 3) / 1536;
    const int col = cc % G3;
    const int kq  = cc / G3;
    const int k = kc * 32 + kq * 8 + e;
    const float v = (k < EMB) ? wih[(size_t)col * EMB + k] : whh[(size_t)col * MEM + (k - EMB)];
    outw[i] = f2b(v);
  } else if (i < nTot) {
    const int j = i - nJ;
    const int r = j >> 9, k = j & 511;
    outw[i] = f2b(wcls[(size_t)r * CLS_K + k]);
  }
}

__global__ void bitmap_set_kernel(const int* __restrict__ ids, unsigned char* __restrict__ bm, int n) {
  int i = blockIdx.x * blockDim.x + threadIdx.x;
  if (i < n) bm[ids[i]] = 1;
}

__global__ void copy_bank_kernel(const f32x4* __restrict__ src, f32x4* __restrict__ dst,
                                 const unsigned char* __restrict__ bm, int n4) {
  int i = blockIdx.x * blockDim.x + threadIdx.x;
  int stride = gridDim.x * blockDim.x;
  for (; i < n4; i += stride) {
    if (bm && bm[i >> 5]) continue;
    dst[i] = src[i];
  }
}

template <bool ASYNC>
__global__ __launch_bounds__(NTHR, 4)
void fused_gru_kernel(const float* __restrict__ emb, const int* __restrict__ ids,
                      const float* __restrict__ bank,
                      const float* __restrict__ Wihf, const float* __restrict__ Whhf,
                      const float* __restrict__ bih,  const float* __restrict__ bhh,
                      const float* __restrict__ Wcls, const float* __restrict__ bcls,
                      const short* __restrict__ Wb,
                      float* __restrict__ out_logits, float* __restrict__ out_bank, int N) {
  __shared__ __align__(16) char smem[SMEM_SZ];

  const int t   = threadIdx.x;
  const int l   = t & 63;
  const int w   = t >> 6;       // 0..7
  const int wr  = w >> 2;       // row group (32 rows)
  const int wc  = w & 3;        // col group (32 m-cols)
  const int lk2 = l >> 5;
  const int l31 = l & 31;
  const int r0  = blockIdx.x * ROWS;

  // ---- epilogue per-lane row (lane l <-> block row l) ----
  int growE = r0 + l; if (growE > N - 1) growE = N - 1;
  const int gidE0 = ids[growE];

  // ---- A staging: 8 lanes/row; lane covers row w*8+(l>>3), source chunk XOR-pre-swizzled ----
  const int rowS = w * 8 + (l >> 3);
  const int chS  = (l & 7) ^ ((l >> 3) & 7);     // source chunk for this lane (involution)
  int growS = r0 + rowS; if (growS > N - 1) growS = N - 1;
  const int gidS = ids[growS];
  const float* pEmbRow  = emb  + (size_t)growS * EMB + chS * 4;
  const float* pBankRow = bank + (size_t)gidS  * MEM + chS * 4;

  // ---- stage cls tables ----
  if (t < 128) {
    short8 v;
    if constexpr (ASYNC) v = *(const short8*)(Wb + WB_CLS + t * 8);
    else {
      const int r = t >> 6, k = (t & 63) * 8;
      const float* p = Wcls + (size_t)r * CLS_K + k;
      v = cvt8(*(const f32x4*)p, *(const f32x4*)(p + 4));
    }
    *(short8*)(smem + OFF_CLS + t * 16) = v;
  } else if (t < 384) {
    const int i = t - 128;
    const int r = i >> 7, m = i & 127;
    ((float*)(smem + OFF_CLSM))[r * 128 + m] = Wcls[(size_t)r * CLS_K + EMB + m];
  }

  const int mcol = wc * 32 + l31;
  const float birv = bih[mcol] + bhh[mcol];
  const float bizv = bih[MEM + mcol] + bhh[MEM + mcol];
  const float binv = bih[2 * MEM + mcol];
  const float bhnv = bhh[2 * MEM + mcol];

  auto STAGE = [&](int kc) {
    const int buf = kc & 1;
    // A: lane-coalesced within rows (8x128B runs), XOR-pre-swizzled source
    const float* srcA = (kc < 16) ? (pEmbRow + kc * 32) : (pBankRow + (kc - 16) * 32);
    gll16(srcA, smem + OFF_A + buf * 8192 + w * 1024);
    if constexpr (ASYNC) {
      // B: wb is in tile order -> each wave reads 1KB consecutive (per-lane +l*16B)
      const short* wbk = Wb + (size_t)kc * 12288;
#pragma unroll
      for (int s = 0; s < 3; ++s)
        gll16(wbk + (s * 512 + w * 64 + l) * 8,
              smem + OFF_B + buf * 24576 + (s * 512 + w * 64) * 16);
    } else {
#pragma unroll
      for (int s = 0; s < 3; ++s) {
        const int g = s * 512 + w * 64 + l;       // chunk = kq*384 + col
        const int col = g % G3, kq = g / G3;
        const int k = kc * 32 + kq * 8;
        const float* p = (k < EMB) ? (Wihf + (size_t)col * EMB + k)
                                   : (Whhf + (size_t)col * MEM + (k - EMB));
        short8 v = cvt8(*(const f32x4*)p, *(const f32x4*)(p + 4));
        *(short8*)(smem + OFF_B + buf * 24576 + g * 16) = v;
      }
    }
  };

  STAGE(0);
  __syncthreads();   // buf0 ready

  f32x16 accR = {}, accZ = {}, accIN = {}, accHN = {};
  float clsL0 = 0.f, clsL1 = 0.f;

  const int arow = wr * 32 + l31;
  const int aswz = arow & 7;
  const int bOffC = lk2 * 6144 + (wc * 32 + l31) * 16;   // + buf*24576 + ks*12288

#pragma unroll
  for (int kc = 0; kc < NKS; ++kc) {
    const int buf = kc & 1;
    if (kc + 1 < NKS) STAGE(kc + 1);    // fills buf^1 while we read buf

    const char* ap = smem + OFF_A + buf * 8192 + arow * 128;
    const char* bp = smem + OFF_B + buf * 24576;
    __builtin_amdgcn_s_setprio(1);      // favor this wave through the LDS->MFMA cluster
#pragma unroll
    for (int ks = 0; ks < 2; ++ks) {
      const int c0 = ks * 4 + lk2 * 2;
      const f32x4 av0 = *(const f32x4*)(ap + ((c0 ^ aswz) << 4));
      const f32x4 av1 = *(const f32x4*)(ap + (((c0 + 1) ^ aswz) << 4));
      const short8 af = cvt8(av0, av1);
      if (wc == 0 && kc < 16) {         // emb-logit VALU dot on col-group 0
        const short8 w0 = *(const short8*)(smem + OFF_CLS + kc * 64 + ks * 32 + lk2 * 16);
        const short8 w1 = *(const short8*)(smem + OFF_CLS + 1024 + kc * 64 + ks * 32 + lk2 * 16);
#pragma unroll
        for (int i = 0; i < 4; ++i) {
          clsL0 += av0[i] * b2f(w0[i]) + av1[i] * b2f(w0[i + 4]);
          clsL1 += av0[i] * b2f(w1[i]) + av1[i] * b2f(w1[i + 4]);
        }
      }
      const short8 b0 = *(const short8*)(bp + bOffC + ks * 12288);
      const short8 b1 = *(const short8*)(bp + bOffC + ks * 12288 + 2048);
      const short8 b2 = *(const short8*)(bp + bOffC + ks * 12288 + 4096);
      accR = __builtin_amdgcn_mfma_f32_32x32x16_bf16(af, b0, accR, 0, 0, 0);
      accZ = __builtin_amdgcn_mfma_f32_32x32x16_bf16(af, b1, accZ, 0, 0, 0);
      if (kc < 16) accIN = __builtin_amdgcn_mfma_f32_32x32x16_bf16(af, b2, accIN, 0, 0, 0);
      else         accHN = __builtin_amdgcn_mfma_f32_32x32x16_bf16(af, b2, accHN, 0, 0, 0);
    }
    __builtin_amdgcn_s_setprio(0);
    __syncthreads();   // buf^1 staged; buf consumed
  }

  // ---------------- GRU epilogue: math -> nv tile in LDS ----------------
  float* nvT = (float*)smem;          // [64][132] f32 (reuses A+B region)
  float hp[16];
#pragma unroll
  for (int j = 0; j < 16; ++j) {
    const int row32 = (j & 3) + 8 * (j >> 2) + 4 * lk2;    // 32x32 C/D row map
    const int gid = __shfl(gidE0, wr * 32 + row32);
    hp[j] = bank[(size_t)gid * MEM + mcol];
  }
#pragma unroll
  for (int j = 0; j < 16; ++j) {
    const int row32 = (j & 3) + 8 * (j >> 2) + 4 * lk2;
    const int row = wr * 32 + row32;
    const float rg = sigm(accR[j] + birv);
    const float zg = sigm(accZ[j] + bizv);
    const float ng = tanhfast(accIN[j] + binv + rg * (accHN[j] + bhnv));
    nvT[row * 132 + mcol] = (1.f - zg) * ng + zg * hp[j];
  }
  if (wc == 0) {
    const float e0 = clsL0 + __shfl_xor(clsL0, 32);
    const float e1 = clsL1 + __shfl_xor(clsL1, 32);
    if (l < 32) {
      float* elp = (float*)(smem + OFF_ELP);
      elp[(wr * 32 + l) * 2 + 0] = e0;
      elp[(wr * 32 + l) * 2 + 1] = e1;
    }
  }
  __syncthreads();

  // ---------------- coalesced scatter + logits ----------------
  {
    const int row = t >> 3, q = t & 7;
    const int gid = __shfl(gidE0, row);
    const f32x4 v0 = *(const f32x4*)(nvT + row * 132 + q * 16);
    const f32x4 v1 = *(const f32x4*)(nvT + row * 132 + q * 16 + 4);
    const f32x4 v2 = *(const f32x4*)(nvT + row * 132 + q * 16 + 8);
    const f32x4 v3 = *(const f32x4*)(nvT + row * 132 + q * 16 + 12);
    float* dst = out_bank + (size_t)gid * MEM + q * 16;
    *(f32x4*)dst = v0; *(f32x4*)(dst + 4) = v1; *(f32x4*)(dst + 8) = v2; *(f32x4*)(dst + 12) = v3;

    const float* cm0 = (const float*)(smem + OFF_CLSM) + q * 16;
    const float* cm1 = (const float*)(smem + OFF_CLSM) + 128 + q * 16;
    float lp0 = 0.f, lp1 = 0.f;
#pragma unroll
    for (int i = 0; i < 4; ++i) {
      lp0 += v0[i] * cm0[i] + v1[i] * cm0[4 + i] + v2[i] * cm0[8 + i] + v3[i] * cm0[12 + i];
      lp1 += v0[i] * cm1[i] + v1[i] * cm1[4 + i] + v2[i] * cm1[8 + i] + v3[i] * cm1[12 + i];
    }
#pragma unroll
    for (int s = 1; s < 8; s <<= 1) { lp0 += __shfl_xor(lp0, s); lp1 += __shfl_xor(lp1, s); }
    if (q == 0 && r0 + row < N) {
      const float* elp = (const float*)(smem + OFF_ELP);
      out_logits[(size_t)(r0 + row) * 2 + 0] = lp0 + elp[row * 2 + 0] + bcls[0];
      out_logits[(size_t)(r0 + row) * 2 + 1] = lp1 + elp[row * 2 + 1] + bcls[1];
    }
  }
}

extern "C" void kernel_launch(void* const* d_in, const int* in_sizes, int n_in,
                              void* d_out, int out_size, void* d_ws, size_t ws_size,
                              hipStream_t stream) {
  const float* emb  = (const float*)d_in[0];
  const int*   ids  = (const int*)d_in[1];
  const float* bank = (const float*)d_in[2];
  const float* wih  = (const float*)d_in[3];
  const float* whh  = (const float*)d_in[4];
  const float* bih  = (const float*)d_in[5];
  const float* bhh  = (const float*)d_in[6];
  const float* wcls = (const float*)d_in[7];
  const float* bcls = (const float*)d_in[8];

  const int N          = in_sizes[1];
  const int bank_elems = in_sizes[2];
  const int bank_rows  = bank_elems / MEM;
  const int n4         = bank_elems / 4;

  float* out_logits = (float*)d_out;
  float* out_bank   = (float*)d_out + (size_t)N * 2;

  const int wtot = G3 * KJ + 2 * EMB;
  const size_t wbytes  = (size_t)wtot * sizeof(short);
  const size_t bmbytes = ((size_t)bank_rows + 15) & ~15ull;

  const bool haveW  = ws_size >= wbytes;
  const bool haveBM = ws_size >= wbytes + bmbytes;

  short* wb = (short*)d_ws;
  unsigned char* bm = (unsigned char*)d_ws + wbytes;

  // 1) weight prep (tile-order layout for coalesced staging)
  if (haveW)
    prep_w_kernel<<<(wtot + 255) / 256, 256, 0, stream>>>(wih, whh, wcls, wb);

  // 2) fused joint-K GEMM (fully-unrolled K loop, 2-buf, 2 blocks/CU)
  const int nb = (N + ROWS - 1) / ROWS;
  if (haveW)
    fused_gru_kernel<true><<<nb, NTHR, 0, stream>>>(emb, ids, bank, wih, whh, bih, bhh,
                                                    wcls, bcls, wb, out_logits, out_bank, N);
  else
    fused_gru_kernel<false><<<nb, NTHR, 0, stream>>>(emb, ids, bank, wih, whh, bih, bhh,
                                                     wcls, bcls, nullptr, out_logits, out_bank, N);

  // 3) copy non-active bank rows (disjoint from scatter rows)
  if (haveBM) {
    hipMemsetAsync(bm, 0, bmbytes, stream);
    bitmap_set_kernel<<<(N + 255) / 256, 256, 0, stream>>>(ids, bm, N);
    copy_bank_kernel<<<4096, 256, 0, stream>>>((const f32x4*)bank, (f32x4*)out_bank, bm, n4);
  } else {
    copy_bank_kernel<<<4096, 256, 0, stream>>>((const f32x4*)bank, (f32x4*)out_bank, nullptr, n4);
  }
}